// Round 1
// baseline (7896.948 us; speedup 1.0000x reference)
//
#include <hip/hip_runtime.h>

// LSTM: B=H=1024, S=128, I=1024.
// Round 3: persistent-weights recurrence kernel.
//  - Wh (4 gates x 16 cols x 1024 K = 128KB) resident in LDS per block, loaded once per chunk.
//  - No intra-step barriers: A-frags (h rows) read directly from global (L2/L3),
//    B-frags from swizzled LDS. c kept in registers across all steps of a chunk.
//  - Steps separated by a device-scope atomic grid barrier (256 blocks == 256 CUs,
//    128KB LDS forces 1 block/CU so all blocks are co-resident).
// ws layout: wT 16MB | bias 16KB @16M | bar @16M+32K | h0 @17M | h1 @19M | c @21M (4MB)
//            | xb (Tc*2MB) @25M | xp (Tc*8MB) after.

#define Hdim 1024
#define Sdim 128
#define NBLK 256

typedef __attribute__((ext_vector_type(8))) short short8;
typedef __attribute__((ext_vector_type(4))) float floatx4;

#define GLDS(gp, lp)                                                     \
  __builtin_amdgcn_global_load_lds(                                      \
      (const __attribute__((address_space(1))) void*)(gp),               \
      (__attribute__((address_space(3))) void*)(lp), 16, 0, 0)

static __device__ __forceinline__ short f2bf(float f) {
  unsigned u = __float_as_uint(f);
  u += 0x7fffu + ((u >> 16) & 1u);
  return (short)(u >> 16);
}
static __device__ __forceinline__ float bf2f(unsigned short u) {
  return __uint_as_float((unsigned)u << 16);
}

// ---- weight transpose + convert: dst[h][k] = src[k][h] (bf16) ----
__global__ __launch_bounds__(256) void wtrans(const float* __restrict__ src,
                                              unsigned short* __restrict__ dst) {
  __shared__ float tile[32][33];
  int h0 = blockIdx.x * 32, k0 = blockIdx.y * 32;
  int tx = threadIdx.x & 31, ty = threadIdx.x >> 5;
#pragma unroll
  for (int r = ty; r < 32; r += 8)
    tile[r][tx] = src[((size_t)(k0 + r) << 10) + h0 + tx];
  __syncthreads();
#pragma unroll
  for (int r = ty; r < 32; r += 8)
    dst[((size_t)(h0 + r) << 10) + k0 + tx] = (unsigned short)f2bf(tile[tx][r]);
}

// ---- combined bias ----
__global__ void bias_combine(const float* __restrict__ b0, const float* __restrict__ b1,
                             const float* __restrict__ b2, const float* __restrict__ b3,
                             const float* __restrict__ b4, const float* __restrict__ b5,
                             const float* __restrict__ b6, const float* __restrict__ b7,
                             float* __restrict__ bias_c) {
  int i = blockIdx.x * 256 + threadIdx.x;
  int g = i >> 10, h = i & 1023;
  const float *pa, *pb;
  switch (g) {
    case 0: pa = b0; pb = b1; break;
    case 1: pa = b2; pb = b3; break;
    case 2: pa = b4; pb = b5; break;
    default: pa = b6; pb = b7; break;
  }
  bias_c[i] = pa[h] + pb[h];
}

// ---- x fp32 -> xb bf16, chunk layout xb[b][tc][k] ----
__global__ __launch_bounds__(256) void xconv(const float* __restrict__ x,
                                             unsigned short* __restrict__ xb,
                                             int t0, int Tcur) {
  int tc = blockIdx.y;
  int tid8 = (blockIdx.x * 256 + threadIdx.x) * 8;
  int b = tid8 >> 10, k = tid8 & 1023;
  const float* src = x + ((((size_t)b << 7) + t0 + tc) << 10) + k;
  floatx4 f0 = *(const floatx4*)src;
  floatx4 f1 = *(const floatx4*)(src + 4);
  short8 o;
#pragma unroll
  for (int j = 0; j < 4; ++j) {
    o[j] = f2bf(f0[j]);
    o[4 + j] = f2bf(f1[j]);
  }
  *(short8*)(xb + (((size_t)b * Tcur + tc) << 10) + k) = o;
}

// ---- big GEMM: xp[tc][b][g*1024+h] = xb[b][tc][:] @ Wx_g[:, h] (bf16 out) ----
__global__ __launch_bounds__(256) void xgemm(const unsigned short* __restrict__ xb,
                                             const unsigned short* __restrict__ wT,
                                             unsigned short* __restrict__ xp,
                                             int Tcur) {
  __shared__ unsigned short As[128 * 32];
  __shared__ unsigned short Bs[128 * 32];
  int tid = threadIdx.x;
  int wave = tid >> 6, lane = tid & 63;
  int ln = lane & 15, lq = lane >> 4;
  int wm = wave & 1, wn = wave >> 1;
  int srow = lane >> 2, scol = (lane & 3) * 8;
  int nt = blockIdx.x;
  int g = nt >> 3;
  int h0 = (nt & 7) * 128;
  int mt = blockIdx.y;
  int tc = mt >> 3;
  int b0 = (mt & 7) * 128;
  const unsigned short* wx = wT + ((size_t)(2 * g) << 20);

  floatx4 acc[4][4];
#pragma unroll
  for (int i = 0; i < 4; ++i)
#pragma unroll
    for (int j = 0; j < 4; ++j) acc[i][j] = (floatx4){0.f, 0.f, 0.f, 0.f};

#pragma unroll 1
  for (int k0 = 0; k0 < 1024; k0 += 32) {
    __syncthreads();
#pragma unroll
    for (int i = 0; i < 2; ++i) {
      int q = wave * 2 + i;
      GLDS(xb + (((size_t)(b0 + q * 16 + srow) * Tcur + tc) << 10) + k0 + scol,
           (char*)As + q * 1024 + lane * 16);
      GLDS(wx + ((size_t)(h0 + q * 16 + srow) << 10) + k0 + scol,
           (char*)Bs + q * 1024 + lane * 16);
    }
    __syncthreads();
    short8 a[4], b[4];
#pragma unroll
    for (int i = 0; i < 4; ++i)
      a[i] = *(const short8*)(As + (wm * 64 + i * 16 + ln) * 32 + lq * 8);
#pragma unroll
    for (int j = 0; j < 4; ++j)
      b[j] = *(const short8*)(Bs + (wn * 64 + j * 16 + ln) * 32 + lq * 8);
#pragma unroll
    for (int i = 0; i < 4; ++i)
#pragma unroll
      for (int j = 0; j < 4; ++j)
        acc[i][j] = __builtin_amdgcn_mfma_f32_16x16x32_bf16(a[i], b[j], acc[i][j], 0, 0, 0);
  }

  size_t rowbase = (size_t)tc << 10;
#pragma unroll
  for (int i = 0; i < 4; ++i) {
    int brow = b0 + wm * 64 + i * 16 + lq * 4;
#pragma unroll
    for (int j = 0; j < 4; ++j) {
      int col = g * 1024 + h0 + wn * 64 + j * 16 + ln;
#pragma unroll
      for (int r = 0; r < 4; ++r)
        xp[((rowbase + brow + r) << 12) + col] = (unsigned short)f2bf(acc[i][j][r]);
    }
  }
}

// ---- persistent recurrence: Tcur steps, Wh resident in LDS, grid barrier between steps ----
// Block: 256 b-rows x 16 h-cols x 4 gates. Grid: 64 hc-tiles x 4 m-tiles = 256 = #CUs.
// 128KB LDS -> exactly 1 block/CU -> all blocks co-resident (required for the barrier).
__global__ __launch_bounds__(512, 2) void lstm_persist(
    const unsigned short* __restrict__ hA, unsigned short* __restrict__ hB,
    float* __restrict__ c_ws, const unsigned short* __restrict__ wT,
    const float* __restrict__ bias_c, const unsigned short* __restrict__ xp,
    float* __restrict__ out, unsigned* __restrict__ bar, unsigned bar_base,
    int t0, int Tcur, int save_c) {
  __shared__ unsigned short Wsh[4 * 16 * 1024];  // 128 KB, XOR-swizzled rows

  const int tid = threadIdx.x;
  const int bid = blockIdx.x;
  const int wave = tid >> 6, lane = tid & 63;
  const int ln = lane & 15, lq = lane >> 4;
  const int hc0 = (bid & 63) << 4;     // 16 h-cols
  const int m0 = (bid >> 6) << 8;      // 256 b-rows

  // ---- stage Wh slice once: Wsh[g][hc][k], byte ^= (hc&7)<<4 (kills 2KB-stride conflicts)
  for (int c = tid; c < 8192; c += 512) {
    int g = c >> 11;
    int r = c & 2047;
    int hc = r >> 7;
    int kc = r & 127;
    short8 v = *(const short8*)(wT + (((size_t)(2 * g + 1)) << 20) +
                                ((size_t)(hc0 + hc) << 10) + kc * 8);
    unsigned byte = ((unsigned)(g * 16 + hc) << 11) + (unsigned)kc * 16;
    byte ^= (unsigned)(hc & 7) << 4;
    *(short8*)((char*)Wsh + byte) = v;
  }

  const int colh = hc0 + ln;
  const float bi = bias_c[colh];
  const float bff = bias_c[1024 + colh];
  const float bgc = bias_c[2048 + colh];
  const float bo = bias_c[3072 + colh];

  // c lives in registers for the whole chunk
  float creg[2][4];
#pragma unroll
  for (int i = 0; i < 2; ++i) {
    int row = m0 + wave * 32 + i * 16 + lq * 4;
#pragma unroll
    for (int r = 0; r < 4; ++r)
      creg[i][r] = c_ws[((size_t)(row + r) << 10) + colh];
  }

  __syncthreads();  // Wsh ready

  const unsigned short* hp = hA;
  unsigned short* hn = hB;

  for (int t = 0; t < Tcur; ++t) {
    floatx4 acc[4][2];
#pragma unroll
    for (int g = 0; g < 4; ++g)
#pragma unroll
      for (int i = 0; i < 2; ++i) acc[g][i] = (floatx4){0.f, 0.f, 0.f, 0.f};

    // K-loop: no barriers. A direct from global h, B from resident LDS.
#pragma unroll 4
    for (int k0 = 0; k0 < 1024; k0 += 32) {
      short8 a[2], b[4];
#pragma unroll
      for (int i = 0; i < 2; ++i)
        a[i] = *(const short8*)(hp + ((size_t)(m0 + wave * 32 + i * 16 + ln) << 10) +
                                k0 + lq * 8);
#pragma unroll
      for (int g = 0; g < 4; ++g) {
        unsigned byte = (((unsigned)(g * 16 + ln) << 11) + (unsigned)(k0 + lq * 8) * 2) ^
                        ((unsigned)(ln & 7) << 4);
        b[g] = *(const short8*)((const char*)Wsh + byte);
      }
#pragma unroll
      for (int g = 0; g < 4; ++g)
#pragma unroll
        for (int i = 0; i < 2; ++i)
          acc[g][i] = __builtin_amdgcn_mfma_f32_16x16x32_bf16(a[i], b[g], acc[g][i], 0, 0, 0);
    }

    // fused LSTM epilogue (C/D layout: col=lane&15, row=lq*4+r)
    const int lastg = (t0 + t == Sdim - 1);
#pragma unroll
    for (int i = 0; i < 2; ++i) {
      int rbase = m0 + wave * 32 + i * 16 + lq * 4;
#pragma unroll
      for (int r = 0; r < 4; ++r) {
        int row = rbase + r;
        size_t xoff = ((((size_t)t) << 10) + row) << 12;
        float pi = acc[0][i][r] + bf2f(xp[xoff + colh]) + bi;
        float pf = acc[1][i][r] + bf2f(xp[xoff + 1024 + colh]) + bff;
        float pg = acc[2][i][r] + bf2f(xp[xoff + 2048 + colh]) + bgc;
        float po = acc[3][i][r] + bf2f(xp[xoff + 3072 + colh]) + bo;
        float gi = 1.f / (1.f + __expf(-pi));
        float gf = 1.f / (1.f + __expf(-pf));
        float gg = 2.f / (1.f + __expf(-2.f * pg)) - 1.f;
        float go = 1.f / (1.f + __expf(-po));
        float cn = gf * creg[i][r] + gi * gg;
        float hnv = go * (2.f / (1.f + __expf(-2.f * cn)) - 1.f);
        creg[i][r] = cn;
        size_t idx = ((size_t)row << 10) + colh;
        hn[idx] = (unsigned short)f2bf(hnv);
        if (lastg) {
          out[idx] = hnv;
          out[(1u << 20) + idx] = cn;
        }
      }
    }

    // grid barrier between steps (skip after the chunk's last step; kernel
    // boundary provides the sync there). Monotonic counter across chunks.
    if (t < Tcur - 1) {
      __syncthreads();  // all waves' hn stores are in L2 (vmcnt drained)
      if (tid == 0) {
        __threadfence();  // agent release: write back XCD L2
        __hip_atomic_fetch_add(bar, 1u, __ATOMIC_RELAXED, __HIP_MEMORY_SCOPE_AGENT);
        unsigned tgt = bar_base + (unsigned)NBLK * (unsigned)(t + 1);
        while (__hip_atomic_load(bar, __ATOMIC_RELAXED, __HIP_MEMORY_SCOPE_AGENT) < tgt)
          __builtin_amdgcn_s_sleep(2);
        __threadfence();  // agent acquire: invalidate stale L1/L2 lines
      }
      __syncthreads();
    }

    unsigned short* tmp = hn;
    hn = (unsigned short*)hp;
    hp = tmp;
  }

  if (save_c) {
#pragma unroll
    for (int i = 0; i < 2; ++i) {
      int row = m0 + wave * 32 + i * 16 + lq * 4;
#pragma unroll
      for (int r = 0; r < 4; ++r)
        c_ws[((size_t)(row + r) << 10) + colh] = creg[i][r];
    }
  }
}

extern "C" void kernel_launch(void* const* d_in, const int* in_sizes, int n_in,
                              void* d_out, int out_size, void* d_ws, size_t ws_size,
                              hipStream_t stream) {
  const float* x = (const float*)d_in[0];
  char* ws = (char*)d_ws;
  unsigned short* wT = (unsigned short*)ws;                        // 16 MB
  float* bias_c = (float*)(ws + (16u << 20));                      // 16 KB
  unsigned* bar = (unsigned*)(ws + (16u << 20) + (32u << 10));     // barrier counter
  unsigned short* hb0 = (unsigned short*)(ws + (17u << 20));       // 2 MB
  unsigned short* hb1 = (unsigned short*)(ws + (19u << 20));       // 2 MB
  float* c_ws = (float*)(ws + (21u << 20));                        // 4 MB
  unsigned short* xb = (unsigned short*)(ws + (25u << 20));        // Tc*2 MB

  size_t base = 25u << 20;
  size_t per_t = 10u << 20;  // xb 2MB + xp 8MB per step
  int Tc = 1;
  if (ws_size > base + per_t) {
    size_t t = (ws_size - base) / per_t;
    Tc = t > 128 ? 128 : (int)t;
  }
  unsigned short* xp = xb + ((size_t)Tc << 20);

  for (int j = 0; j < 8; ++j)
    wtrans<<<dim3(32, 32), 256, 0, stream>>>((const float*)d_in[1 + j],
                                             wT + ((size_t)j << 20));
  bias_combine<<<16, 256, 0, stream>>>(
      (const float*)d_in[9], (const float*)d_in[10], (const float*)d_in[11],
      (const float*)d_in[12], (const float*)d_in[13], (const float*)d_in[14],
      (const float*)d_in[15], (const float*)d_in[16], bias_c);

  hipMemsetAsync(hb0, 0, 2u << 20, stream);
  hipMemsetAsync(c_ws, 0, 4u << 20, stream);
  hipMemsetAsync(bar, 0, 256, stream);

  float* out = (float*)d_out;
  unsigned short* hcur = hb0;
  unsigned short* hnxt = hb1;
  unsigned barcnt = 0;
  for (int t0 = 0; t0 < Sdim; t0 += Tc) {
    int Tcur = (Sdim - t0) < Tc ? (Sdim - t0) : Tc;
    xconv<<<dim3(512, Tcur), 256, 0, stream>>>(x, xb, t0, Tcur);
    xgemm<<<dim3(32, Tcur * 8), 256, 0, stream>>>(xb, wT, xp, Tcur);
    int save_c = (t0 + Tcur < Sdim) ? 1 : 0;
    lstm_persist<<<dim3(NBLK), dim3(512), 0, stream>>>(
        hcur, hnxt, c_ws, wT, bias_c, xp, out, bar,
        (unsigned)NBLK * barcnt, t0, Tcur, save_c);
    barcnt += (unsigned)(Tcur - 1);
    if (Tcur & 1) {
      unsigned short* tmp = hcur;
      hcur = hnxt;
      hnxt = tmp;
    }
  }
}

// Round 6
// 5724.186 us; speedup vs baseline: 1.3796x; 1.3796x over previous
//
#include <hip/hip_runtime.h>

// LSTM: B=H=1024, S=128, I=1024.
// Round 4 (resubmit x4; R2-R5 benches never acquired a GPU): latency surgery
// on the persistent recurrence kernel.
//  - h stores are write-through (agent-scope relaxed atomic stores) -> release needs
//    no buffer_wbl2 L2 walk; acquire is an invalidate-only fence. No __threadfence().
//  - xp gate-interleaved ([row][h*4+g]) + prefetched into registers at step start;
//    K-loop hides the HBM latency.
//  - K-loop software-pipelined (2 named a-buffers, 64-k chunks, static indexing).
// ws layout: wT 16MB | bias 16KB @16M | bar @16M+32K | h0 @17M | h1 @19M | c @21M (4MB)
//            | xb (Tc*2MB) @25M | xp (Tc*8MB) after.

#define Hdim 1024
#define Sdim 128
#define NBLK 256

typedef __attribute__((ext_vector_type(8))) short short8;
typedef __attribute__((ext_vector_type(4))) float floatx4;
typedef __attribute__((ext_vector_type(4))) unsigned short ushort4v;

#define GLDS(gp, lp)                                                     \
  __builtin_amdgcn_global_load_lds(                                      \
      (const __attribute__((address_space(1))) void*)(gp),               \
      (__attribute__((address_space(3))) void*)(lp), 16, 0, 0)

static __device__ __forceinline__ short f2bf(float f) {
  unsigned u = __float_as_uint(f);
  u += 0x7fffu + ((u >> 16) & 1u);
  return (short)(u >> 16);
}
static __device__ __forceinline__ float bf2f(unsigned short u) {
  return __uint_as_float((unsigned)u << 16);
}

// ---- weight transpose + convert: dst[h][k] = src[k][h] (bf16) ----
__global__ __launch_bounds__(256) void wtrans(const float* __restrict__ src,
                                              unsigned short* __restrict__ dst) {
  __shared__ float tile[32][33];
  int h0 = blockIdx.x * 32, k0 = blockIdx.y * 32;
  int tx = threadIdx.x & 31, ty = threadIdx.x >> 5;
#pragma unroll
  for (int r = ty; r < 32; r += 8)
    tile[r][tx] = src[((size_t)(k0 + r) << 10) + h0 + tx];
  __syncthreads();
#pragma unroll
  for (int r = ty; r < 32; r += 8)
    dst[((size_t)(h0 + r) << 10) + k0 + tx] = (unsigned short)f2bf(tile[tx][r]);
}

// ---- combined bias ----
__global__ void bias_combine(const float* __restrict__ b0, const float* __restrict__ b1,
                             const float* __restrict__ b2, const float* __restrict__ b3,
                             const float* __restrict__ b4, const float* __restrict__ b5,
                             const float* __restrict__ b6, const float* __restrict__ b7,
                             float* __restrict__ bias_c) {
  int i = blockIdx.x * 256 + threadIdx.x;
  int g = i >> 10, h = i & 1023;
  const float *pa, *pb;
  switch (g) {
    case 0: pa = b0; pb = b1; break;
    case 1: pa = b2; pb = b3; break;
    case 2: pa = b4; pb = b5; break;
    default: pa = b6; pb = b7; break;
  }
  bias_c[i] = pa[h] + pb[h];
}

// ---- x fp32 -> xb bf16, chunk layout xb[b][tc][k] ----
__global__ __launch_bounds__(256) void xconv(const float* __restrict__ x,
                                             unsigned short* __restrict__ xb,
                                             int t0, int Tcur) {
  int tc = blockIdx.y;
  int tid8 = (blockIdx.x * 256 + threadIdx.x) * 8;
  int b = tid8 >> 10, k = tid8 & 1023;
  const float* src = x + ((((size_t)b << 7) + t0 + tc) << 10) + k;
  floatx4 f0 = *(const floatx4*)src;
  floatx4 f1 = *(const floatx4*)(src + 4);
  short8 o;
#pragma unroll
  for (int j = 0; j < 4; ++j) {
    o[j] = f2bf(f0[j]);
    o[4 + j] = f2bf(f1[j]);
  }
  *(short8*)(xb + (((size_t)b * Tcur + tc) << 10) + k) = o;
}

// ---- big GEMM: xp[tc][b][h*4+g] = xb[b][tc][:] @ Wx_g[:, h] (bf16, gate-interleaved) ----
__global__ __launch_bounds__(256) void xgemm(const unsigned short* __restrict__ xb,
                                             const unsigned short* __restrict__ wT,
                                             unsigned short* __restrict__ xp,
                                             int Tcur) {
  __shared__ unsigned short As[128 * 32];
  __shared__ unsigned short Bs[128 * 32];
  int tid = threadIdx.x;
  int wave = tid >> 6, lane = tid & 63;
  int ln = lane & 15, lq = lane >> 4;
  int wm = wave & 1, wn = wave >> 1;
  int srow = lane >> 2, scol = (lane & 3) * 8;
  int nt = blockIdx.x;
  int g = nt >> 3;
  int h0 = (nt & 7) * 128;
  int mt = blockIdx.y;
  int tc = mt >> 3;
  int b0 = (mt & 7) * 128;
  const unsigned short* wx = wT + ((size_t)(2 * g) << 20);

  floatx4 acc[4][4];
#pragma unroll
  for (int i = 0; i < 4; ++i)
#pragma unroll
    for (int j = 0; j < 4; ++j) acc[i][j] = (floatx4){0.f, 0.f, 0.f, 0.f};

#pragma unroll 1
  for (int k0 = 0; k0 < 1024; k0 += 32) {
    __syncthreads();
#pragma unroll
    for (int i = 0; i < 2; ++i) {
      int q = wave * 2 + i;
      GLDS(xb + (((size_t)(b0 + q * 16 + srow) * Tcur + tc) << 10) + k0 + scol,
           (char*)As + q * 1024 + lane * 16);
      GLDS(wx + ((size_t)(h0 + q * 16 + srow) << 10) + k0 + scol,
           (char*)Bs + q * 1024 + lane * 16);
    }
    __syncthreads();
    short8 a[4], b[4];
#pragma unroll
    for (int i = 0; i < 4; ++i)
      a[i] = *(const short8*)(As + (wm * 64 + i * 16 + ln) * 32 + lq * 8);
#pragma unroll
    for (int j = 0; j < 4; ++j)
      b[j] = *(const short8*)(Bs + (wn * 64 + j * 16 + ln) * 32 + lq * 8);
#pragma unroll
    for (int i = 0; i < 4; ++i)
#pragma unroll
      for (int j = 0; j < 4; ++j)
        acc[i][j] = __builtin_amdgcn_mfma_f32_16x16x32_bf16(a[i], b[j], acc[i][j], 0, 0, 0);
  }

  size_t rowbase = (size_t)tc << 10;
#pragma unroll
  for (int i = 0; i < 4; ++i) {
    int brow = b0 + wm * 64 + i * 16 + lq * 4;
#pragma unroll
    for (int j = 0; j < 4; ++j) {
      int hcol = h0 + wn * 64 + j * 16 + ln;
#pragma unroll
      for (int r = 0; r < 4; ++r)
        xp[((rowbase + brow + r) << 12) + (hcol << 2) + g] =
            (unsigned short)f2bf(acc[i][j][r]);
    }
  }
}

// ---- persistent recurrence: Tcur steps, Wh resident in LDS, grid barrier between steps ----
// Block: 256 b-rows x 16 h-cols x 4 gates. Grid: 64 hc-tiles x 4 m-tiles = 256 = #CUs.
// 128KB LDS -> exactly 1 block/CU -> all blocks co-resident (required for the barrier).
__global__ __launch_bounds__(512, 2) void lstm_persist(
    const unsigned short* __restrict__ hA, unsigned short* __restrict__ hB,
    float* __restrict__ c_ws, const unsigned short* __restrict__ wT,
    const float* __restrict__ bias_c, const unsigned short* __restrict__ xp,
    float* __restrict__ out, unsigned* __restrict__ bar, unsigned bar_base,
    int t0, int Tcur, int save_c) {
  __shared__ unsigned short Wsh[4 * 16 * 1024];  // 128 KB, XOR-swizzled rows

  const int tid = threadIdx.x;
  const int bid = blockIdx.x;
  const int wave = tid >> 6, lane = tid & 63;
  const int ln = lane & 15, lq = lane >> 4;
  const int hc0 = (bid & 63) << 4;     // 16 h-cols
  const int m0 = (bid >> 6) << 8;      // 256 b-rows

  // ---- stage Wh slice once: Wsh[g][hc][k], byte ^= (hc&7)<<4 (kills 2KB-stride conflicts)
  for (int c = tid; c < 8192; c += 512) {
    int g = c >> 11;
    int r = c & 2047;
    int hc = r >> 7;
    int kc = r & 127;
    short8 v = *(const short8*)(wT + (((size_t)(2 * g + 1)) << 20) +
                                ((size_t)(hc0 + hc) << 10) + kc * 8);
    unsigned byte = ((unsigned)(g * 16 + hc) << 11) + (unsigned)kc * 16;
    byte ^= (unsigned)(hc & 7) << 4;
    *(short8*)((char*)Wsh + byte) = v;
  }

  const int colh = hc0 + ln;
  const float bi = bias_c[colh];
  const float bff = bias_c[1024 + colh];
  const float bgc = bias_c[2048 + colh];
  const float bo = bias_c[3072 + colh];

  // c lives in registers for the whole chunk
  float creg[2][4];
#pragma unroll
  for (int i = 0; i < 2; ++i) {
    int row = m0 + wave * 32 + i * 16 + lq * 4;
#pragma unroll
    for (int r = 0; r < 4; ++r)
      creg[i][r] = c_ws[((size_t)(row + r) << 10) + colh];
  }

  __syncthreads();  // Wsh ready

  const unsigned short* hp = hA;
  unsigned short* hn = hB;

  floatx4 acc[4][2];
  const unsigned short *hrow0, *hrow1;

  // software-pipeline helpers: chunk = 64 k (2 MFMA sub-steps), static indexing only
  auto loadch = [&](short8 (&buf)[2][2], int c) {
#pragma unroll
    for (int s = 0; s < 2; ++s) {
      buf[s][0] = *(const short8*)(hrow0 + c * 64 + s * 32);
      buf[s][1] = *(const short8*)(hrow1 + c * 64 + s * 32);
    }
  };
  auto compch = [&](short8 (&buf)[2][2], int c) {
#pragma unroll
    for (int s = 0; s < 2; ++s) {
      int kk = c * 64 + s * 32;
#pragma unroll
      for (int g = 0; g < 4; ++g) {
        unsigned byte = (((unsigned)(g * 16 + ln) << 11) + (unsigned)(kk + lq * 8) * 2) ^
                        ((unsigned)(ln & 7) << 4);
        short8 b = *(const short8*)((const char*)Wsh + byte);
#pragma unroll
        for (int i = 0; i < 2; ++i)
          acc[g][i] =
              __builtin_amdgcn_mfma_f32_16x16x32_bf16(buf[s][i], b, acc[g][i], 0, 0, 0);
      }
    }
  };

  for (int t = 0; t < Tcur; ++t) {
    // ---- prefetch this step's xp gate-quads (latency hidden under the K-loop)
    ushort4v xpv[2][4];
#pragma unroll
    for (int i = 0; i < 2; ++i) {
      int rbase = m0 + wave * 32 + i * 16 + lq * 4;
#pragma unroll
      for (int r = 0; r < 4; ++r)
        xpv[i][r] = *(const ushort4v*)(xp + ((((size_t)t << 10) + rbase + r) << 12) +
                                       ((size_t)colh << 2));
    }

#pragma unroll
    for (int g = 0; g < 4; ++g)
#pragma unroll
      for (int i = 0; i < 2; ++i) acc[g][i] = (floatx4){0.f, 0.f, 0.f, 0.f};

    hrow0 = hp + ((size_t)(m0 + wave * 32 + ln) << 10) + lq * 8;
    hrow1 = hrow0 + (16 << 10);

    // ---- K-loop: 16 chunks of 64, depth-2 named-buffer pipeline, no barriers
    short8 aA[2][2], aB[2][2];
    loadch(aA, 0);
    loadch(aB, 1);
#pragma unroll 1
    for (int c = 0; c < 14; c += 2) {
      compch(aA, c);
      loadch(aA, c + 2);
      compch(aB, c + 1);
      loadch(aB, c + 3);
    }
    compch(aA, 14);
    compch(aB, 15);

    // ---- fused LSTM epilogue (C/D layout: col=lane&15, row=lq*4+r)
    const int lastg = (t0 + t == Sdim - 1);
#pragma unroll
    for (int i = 0; i < 2; ++i) {
      int rbase2 = m0 + wave * 32 + i * 16 + lq * 4;
#pragma unroll
      for (int r = 0; r < 4; ++r) {
        int row = rbase2 + r;
        float pi = acc[0][i][r] + bf2f(xpv[i][r][0]) + bi;
        float pf = acc[1][i][r] + bf2f(xpv[i][r][1]) + bff;
        float pg = acc[2][i][r] + bf2f(xpv[i][r][2]) + bgc;
        float po = acc[3][i][r] + bf2f(xpv[i][r][3]) + bo;
        float gi = 1.f / (1.f + __expf(-pi));
        float gf = 1.f / (1.f + __expf(-pf));
        float gg = 2.f / (1.f + __expf(-2.f * pg)) - 1.f;
        float go = 1.f / (1.f + __expf(-po));
        float cn = gf * creg[i][r] + gi * gg;
        float hnv = go * (2.f / (1.f + __expf(-2.f * cn)) - 1.f);
        creg[i][r] = cn;
        size_t idx = ((size_t)row << 10) + colh;
        // write-through store: visible at coherence point once vmcnt drains ->
        // the release fence needs NO buffer_wbl2 L2 walk.
        __hip_atomic_store(&hn[idx], (unsigned short)f2bf(hnv), __ATOMIC_RELAXED,
                           __HIP_MEMORY_SCOPE_AGENT);
        if (lastg) {
          out[idx] = hnv;
          out[(1u << 20) + idx] = cn;
        }
      }
    }

    // ---- grid barrier between steps. Release = vmcnt(0) inside __syncthreads
    // (stores are write-through). Acquire = invalidate-only agent fence.
    if (t < Tcur - 1) {
      __syncthreads();
      if (tid == 0) {
        __hip_atomic_fetch_add(bar, 1u, __ATOMIC_RELAXED, __HIP_MEMORY_SCOPE_AGENT);
        unsigned tgt = bar_base + (unsigned)NBLK * (unsigned)(t + 1);
        while (__hip_atomic_load(bar, __ATOMIC_RELAXED, __HIP_MEMORY_SCOPE_AGENT) < tgt)
          __builtin_amdgcn_s_sleep(2);
        __builtin_amdgcn_fence(__ATOMIC_ACQUIRE, "agent");  // inv L1+L2, no wbl2
      }
      __syncthreads();
    }

    unsigned short* tmp = hn;
    hn = (unsigned short*)hp;
    hp = tmp;
  }

  if (save_c) {
#pragma unroll
    for (int i = 0; i < 2; ++i) {
      int row = m0 + wave * 32 + i * 16 + lq * 4;
#pragma unroll
      for (int r = 0; r < 4; ++r)
        c_ws[((size_t)(row + r) << 10) + colh] = creg[i][r];
    }
  }
}

extern "C" void kernel_launch(void* const* d_in, const int* in_sizes, int n_in,
                              void* d_out, int out_size, void* d_ws, size_t ws_size,
                              hipStream_t stream) {
  const float* x = (const float*)d_in[0];
  char* ws = (char*)d_ws;
  unsigned short* wT = (unsigned short*)ws;                        // 16 MB
  float* bias_c = (float*)(ws + (16u << 20));                      // 16 KB
  unsigned* bar = (unsigned*)(ws + (16u << 20) + (32u << 10));     // barrier counter
  unsigned short* hb0 = (unsigned short*)(ws + (17u << 20));       // 2 MB
  unsigned short* hb1 = (unsigned short*)(ws + (19u << 20));       // 2 MB
  float* c_ws = (float*)(ws + (21u << 20));                        // 4 MB
  unsigned short* xb = (unsigned short*)(ws + (25u << 20));        // Tc*2 MB

  size_t base = 25u << 20;
  size_t per_t = 10u << 20;  // xb 2MB + xp 8MB per step
  int Tc = 1;
  if (ws_size > base + per_t) {
    size_t t = (ws_size - base) / per_t;
    Tc = t > 128 ? 128 : (int)t;
  }
  unsigned short* xp = xb + ((size_t)Tc << 20);

  for (int j = 0; j < 8; ++j)
    wtrans<<<dim3(32, 32), 256, 0, stream>>>((const float*)d_in[1 + j],
                                             wT + ((size_t)j << 20));
  bias_combine<<<16, 256, 0, stream>>>(
      (const float*)d_in[9], (const float*)d_in[10], (const float*)d_in[11],
      (const float*)d_in[12], (const float*)d_in[13], (const float*)d_in[14],
      (const float*)d_in[15], (const float*)d_in[16], bias_c);

  hipMemsetAsync(hb0, 0, 2u << 20, stream);
  hipMemsetAsync(c_ws, 0, 4u << 20, stream);
  hipMemsetAsync(bar, 0, 256, stream);

  float* out = (float*)d_out;
  unsigned short* hcur = hb0;
  unsigned short* hnxt = hb1;
  unsigned barcnt = 0;
  for (int t0 = 0; t0 < Sdim; t0 += Tc) {
    int Tcur = (Sdim - t0) < Tc ? (Sdim - t0) : Tc;
    xconv<<<dim3(512, Tcur), 256, 0, stream>>>(x, xb, t0, Tcur);
    xgemm<<<dim3(32, Tcur * 8), 256, 0, stream>>>(xb, wT, xp, Tcur);
    int save_c = (t0 + Tcur < Sdim) ? 1 : 0;
    lstm_persist<<<dim3(NBLK), dim3(512), 0, stream>>>(
        hcur, hnxt, c_ws, wT, bias_c, xp, out, bar,
        (unsigned)NBLK * barcnt, t0, Tcur, save_c);
    barcnt += (unsigned)(Tcur - 1);
    if (Tcur & 1) {
      unsigned short* tmp = hcur;
      hcur = hnxt;
      hnxt = tmp;
    }
  }
}

// Round 7
// 5298.928 us; speedup vs baseline: 1.4903x; 1.0803x over previous
//
#include <hip/hip_runtime.h>

// LSTM: B=H=1024, S=128, I=1024.
// Round 5: exploit batch-row independence of the recurrence.
//  - h_{t+1}[b,:] depends only on h_t[b,:]  =>  the 4 m-groups (256 rows each)
//    are fully independent. Replace the global 256-block barrier with 4
//    independent 64-block group barriers (4 counters, 4x less contention,
//    decoupled progress).
//  - XCD-pair mapping: mg=(bid&7)>>1 puts each group on XCDs {2g,2g+1}
//    (assuming round-robin bid->XCD; perf-only, correctness unaffected).
//    Group h-exchange becomes 2-XCD-local: L2 refetch 512KB/step not 2MB.
//  - K-loop pipeline depth 2 -> 4 (16 chunks = 4x4 named buffers) to cover
//    post-invalidate LLC latency (~500cy) with ~240cy of in-flight compute.
//  - Keeps R4's verified pieces: write-through h stores + invalidate-only
//    acquire, gate-interleaved xp prefetch, LDS-resident swizzled Wh.
// ws layout: wT 16MB | bias 16KB @16M | bar[4] @16M+32K | h0 @17M | h1 @19M
//            | c @21M (4MB) | xb (Tc*2MB) @25M | xp (Tc*8MB) after.

#define Hdim 1024
#define Sdim 128
#define NBLK 256

typedef __attribute__((ext_vector_type(8))) short short8;
typedef __attribute__((ext_vector_type(4))) float floatx4;
typedef __attribute__((ext_vector_type(4))) unsigned short ushort4v;

#define GLDS(gp, lp)                                                     \
  __builtin_amdgcn_global_load_lds(                                      \
      (const __attribute__((address_space(1))) void*)(gp),               \
      (__attribute__((address_space(3))) void*)(lp), 16, 0, 0)

static __device__ __forceinline__ short f2bf(float f) {
  unsigned u = __float_as_uint(f);
  u += 0x7fffu + ((u >> 16) & 1u);
  return (short)(u >> 16);
}
static __device__ __forceinline__ float bf2f(unsigned short u) {
  return __uint_as_float((unsigned)u << 16);
}

// ---- weight transpose + convert: dst[h][k] = src[k][h] (bf16) ----
__global__ __launch_bounds__(256) void wtrans(const float* __restrict__ src,
                                              unsigned short* __restrict__ dst) {
  __shared__ float tile[32][33];
  int h0 = blockIdx.x * 32, k0 = blockIdx.y * 32;
  int tx = threadIdx.x & 31, ty = threadIdx.x >> 5;
#pragma unroll
  for (int r = ty; r < 32; r += 8)
    tile[r][tx] = src[((size_t)(k0 + r) << 10) + h0 + tx];
  __syncthreads();
#pragma unroll
  for (int r = ty; r < 32; r += 8)
    dst[((size_t)(h0 + r) << 10) + k0 + tx] = (unsigned short)f2bf(tile[tx][r]);
}

// ---- combined bias ----
__global__ void bias_combine(const float* __restrict__ b0, const float* __restrict__ b1,
                             const float* __restrict__ b2, const float* __restrict__ b3,
                             const float* __restrict__ b4, const float* __restrict__ b5,
                             const float* __restrict__ b6, const float* __restrict__ b7,
                             float* __restrict__ bias_c) {
  int i = blockIdx.x * 256 + threadIdx.x;
  int g = i >> 10, h = i & 1023;
  const float *pa, *pb;
  switch (g) {
    case 0: pa = b0; pb = b1; break;
    case 1: pa = b2; pb = b3; break;
    case 2: pa = b4; pb = b5; break;
    default: pa = b6; pb = b7; break;
  }
  bias_c[i] = pa[h] + pb[h];
}

// ---- x fp32 -> xb bf16, chunk layout xb[b][tc][k] ----
__global__ __launch_bounds__(256) void xconv(const float* __restrict__ x,
                                             unsigned short* __restrict__ xb,
                                             int t0, int Tcur) {
  int tc = blockIdx.y;
  int tid8 = (blockIdx.x * 256 + threadIdx.x) * 8;
  int b = tid8 >> 10, k = tid8 & 1023;
  const float* src = x + ((((size_t)b << 7) + t0 + tc) << 10) + k;
  floatx4 f0 = *(const floatx4*)src;
  floatx4 f1 = *(const floatx4*)(src + 4);
  short8 o;
#pragma unroll
  for (int j = 0; j < 4; ++j) {
    o[j] = f2bf(f0[j]);
    o[4 + j] = f2bf(f1[j]);
  }
  *(short8*)(xb + (((size_t)b * Tcur + tc) << 10) + k) = o;
}

// ---- big GEMM: xp[tc][b][h*4+g] = xb[b][tc][:] @ Wx_g[:, h] (bf16, gate-interleaved) ----
__global__ __launch_bounds__(256) void xgemm(const unsigned short* __restrict__ xb,
                                             const unsigned short* __restrict__ wT,
                                             unsigned short* __restrict__ xp,
                                             int Tcur) {
  __shared__ unsigned short As[128 * 32];
  __shared__ unsigned short Bs[128 * 32];
  int tid = threadIdx.x;
  int wave = tid >> 6, lane = tid & 63;
  int ln = lane & 15, lq = lane >> 4;
  int wm = wave & 1, wn = wave >> 1;
  int srow = lane >> 2, scol = (lane & 3) * 8;
  int nt = blockIdx.x;
  int g = nt >> 3;
  int h0 = (nt & 7) * 128;
  int mt = blockIdx.y;
  int tc = mt >> 3;
  int b0 = (mt & 7) * 128;
  const unsigned short* wx = wT + ((size_t)(2 * g) << 20);

  floatx4 acc[4][4];
#pragma unroll
  for (int i = 0; i < 4; ++i)
#pragma unroll
    for (int j = 0; j < 4; ++j) acc[i][j] = (floatx4){0.f, 0.f, 0.f, 0.f};

#pragma unroll 1
  for (int k0 = 0; k0 < 1024; k0 += 32) {
    __syncthreads();
#pragma unroll
    for (int i = 0; i < 2; ++i) {
      int q = wave * 2 + i;
      GLDS(xb + (((size_t)(b0 + q * 16 + srow) * Tcur + tc) << 10) + k0 + scol,
           (char*)As + q * 1024 + lane * 16);
      GLDS(wx + ((size_t)(h0 + q * 16 + srow) << 10) + k0 + scol,
           (char*)Bs + q * 1024 + lane * 16);
    }
    __syncthreads();
    short8 a[4], b[4];
#pragma unroll
    for (int i = 0; i < 4; ++i)
      a[i] = *(const short8*)(As + (wm * 64 + i * 16 + ln) * 32 + lq * 8);
#pragma unroll
    for (int j = 0; j < 4; ++j)
      b[j] = *(const short8*)(Bs + (wn * 64 + j * 16 + ln) * 32 + lq * 8);
#pragma unroll
    for (int i = 0; i < 4; ++i)
#pragma unroll
      for (int j = 0; j < 4; ++j)
        acc[i][j] = __builtin_amdgcn_mfma_f32_16x16x32_bf16(a[i], b[j], acc[i][j], 0, 0, 0);
  }

  size_t rowbase = (size_t)tc << 10;
#pragma unroll
  for (int i = 0; i < 4; ++i) {
    int brow = b0 + wm * 64 + i * 16 + lq * 4;
#pragma unroll
    for (int j = 0; j < 4; ++j) {
      int hcol = h0 + wn * 64 + j * 16 + ln;
#pragma unroll
      for (int r = 0; r < 4; ++r)
        xp[((rowbase + brow + r) << 12) + (hcol << 2) + g] =
            (unsigned short)f2bf(acc[i][j][r]);
    }
  }
}

// ---- persistent recurrence, group-local barriers ----
// 4 independent m-groups (256 rows each); group = (bid&7)>>1 -> XCDs {2g,2g+1}
// under round-robin dispatch. Each group: 64 blocks x (256 rows x 16 h-cols x
// 4 gates). 128KB LDS -> 1 block/CU -> all co-resident.
__global__ __launch_bounds__(512, 2) void lstm_persist(
    const unsigned short* __restrict__ hA, unsigned short* __restrict__ hB,
    float* __restrict__ c_ws, const unsigned short* __restrict__ wT,
    const float* __restrict__ bias_c, const unsigned short* __restrict__ xp,
    float* __restrict__ out, unsigned* __restrict__ bar, unsigned bar_base,
    int t0, int Tcur, int save_c) {
  __shared__ unsigned short Wsh[4 * 16 * 1024];  // 128 KB, XOR-swizzled rows

  const int tid = threadIdx.x;
  const int bid = blockIdx.x;
  const int wave = tid >> 6, lane = tid & 63;
  const int ln = lane & 15, lq = lane >> 4;
  // XCD-pair mapping: group mg on XCDs {2mg, 2mg+1}; bijective over bid 0..255.
  const int mg = (bid & 7) >> 1;                       // m-group 0..3
  const int hc = ((bid >> 3) << 1) | (bid & 1);        // h-tile 0..63
  const int hc0 = hc << 4;                             // 16 h-cols
  const int m0 = mg << 8;                              // 256 b-rows
  unsigned* gbar = bar + (mg << 6);                    // per-group counter, 256B apart

  // ---- stage Wh slice once: Wsh[g][hc][k], byte ^= (hc&7)<<4 (kills 2KB-stride conflicts)
  for (int c = tid; c < 8192; c += 512) {
    int g = c >> 11;
    int r = c & 2047;
    int hcr = r >> 7;
    int kc = r & 127;
    short8 v = *(const short8*)(wT + (((size_t)(2 * g + 1)) << 20) +
                                ((size_t)(hc0 + hcr) << 10) + kc * 8);
    unsigned byte = ((unsigned)(g * 16 + hcr) << 11) + (unsigned)kc * 16;
    byte ^= (unsigned)(hcr & 7) << 4;
    *(short8*)((char*)Wsh + byte) = v;
  }

  const int colh = hc0 + ln;
  const float bi = bias_c[colh];
  const float bff = bias_c[1024 + colh];
  const float bgc = bias_c[2048 + colh];
  const float bo = bias_c[3072 + colh];

  // c lives in registers for the whole chunk
  float creg[2][4];
#pragma unroll
  for (int i = 0; i < 2; ++i) {
    int row = m0 + wave * 32 + i * 16 + lq * 4;
#pragma unroll
    for (int r = 0; r < 4; ++r)
      creg[i][r] = c_ws[((size_t)(row + r) << 10) + colh];
  }

  __syncthreads();  // Wsh ready

  const unsigned short* hp = hA;
  unsigned short* hn = hB;

  floatx4 acc[4][2];
  const unsigned short *hrow0, *hrow1;

  // software-pipeline helpers: chunk = 64 k (2 MFMA sub-steps), static indexing only
  auto loadch = [&](short8 (&buf)[2][2], int c) {
#pragma unroll
    for (int s = 0; s < 2; ++s) {
      buf[s][0] = *(const short8*)(hrow0 + c * 64 + s * 32);
      buf[s][1] = *(const short8*)(hrow1 + c * 64 + s * 32);
    }
  };
  auto compch = [&](short8 (&buf)[2][2], int c) {
#pragma unroll
    for (int s = 0; s < 2; ++s) {
      int kk = c * 64 + s * 32;
#pragma unroll
      for (int g = 0; g < 4; ++g) {
        unsigned byte = (((unsigned)(g * 16 + ln) << 11) + (unsigned)(kk + lq * 8) * 2) ^
                        ((unsigned)(ln & 7) << 4);
        short8 b = *(const short8*)((const char*)Wsh + byte);
#pragma unroll
        for (int i = 0; i < 2; ++i)
          acc[g][i] =
              __builtin_amdgcn_mfma_f32_16x16x32_bf16(buf[s][i], b, acc[g][i], 0, 0, 0);
      }
    }
  };

  for (int t = 0; t < Tcur; ++t) {
    // ---- prefetch this step's xp gate-quads (latency hidden under the K-loop)
    ushort4v xpv[2][4];
#pragma unroll
    for (int i = 0; i < 2; ++i) {
      int rbase = m0 + wave * 32 + i * 16 + lq * 4;
#pragma unroll
      for (int r = 0; r < 4; ++r)
        xpv[i][r] = *(const ushort4v*)(xp + ((((size_t)t << 10) + rbase + r) << 12) +
                                       ((size_t)colh << 2));
    }

#pragma unroll
    for (int g = 0; g < 4; ++g)
#pragma unroll
      for (int i = 0; i < 2; ++i) acc[g][i] = (floatx4){0.f, 0.f, 0.f, 0.f};

    hrow0 = hp + ((size_t)(m0 + wave * 32 + ln) << 10) + lq * 8;
    hrow1 = hrow0 + (16 << 10);

    // ---- K-loop: 16 chunks of 64, depth-4 named-buffer pipeline, no barriers
    short8 aA[2][2], aB[2][2], aC[2][2], aD[2][2];
    loadch(aA, 0);
    loadch(aB, 1);
    loadch(aC, 2);
    loadch(aD, 3);
#pragma unroll 1
    for (int c = 0; c < 12; c += 4) {
      compch(aA, c);
      loadch(aA, c + 4);
      compch(aB, c + 1);
      loadch(aB, c + 5);
      compch(aC, c + 2);
      loadch(aC, c + 6);
      compch(aD, c + 3);
      loadch(aD, c + 7);
    }
    compch(aA, 12);
    compch(aB, 13);
    compch(aC, 14);
    compch(aD, 15);

    // ---- fused LSTM epilogue (C/D layout: col=lane&15, row=lq*4+r)
    const int lastg = (t0 + t == Sdim - 1);
#pragma unroll
    for (int i = 0; i < 2; ++i) {
      int rbase2 = m0 + wave * 32 + i * 16 + lq * 4;
#pragma unroll
      for (int r = 0; r < 4; ++r) {
        int row = rbase2 + r;
        float pi = acc[0][i][r] + bf2f(xpv[i][r][0]) + bi;
        float pf = acc[1][i][r] + bf2f(xpv[i][r][1]) + bff;
        float pg = acc[2][i][r] + bf2f(xpv[i][r][2]) + bgc;
        float po = acc[3][i][r] + bf2f(xpv[i][r][3]) + bo;
        float gi = 1.f / (1.f + __expf(-pi));
        float gf = 1.f / (1.f + __expf(-pf));
        float gg = 2.f / (1.f + __expf(-2.f * pg)) - 1.f;
        float go = 1.f / (1.f + __expf(-po));
        float cn = gf * creg[i][r] + gi * gg;
        float hnv = go * (2.f / (1.f + __expf(-2.f * cn)) - 1.f);
        creg[i][r] = cn;
        size_t idx = ((size_t)row << 10) + colh;
        // write-through store: visible at coherence point once vmcnt drains ->
        // the release needs NO buffer_wbl2 L2 walk.
        __hip_atomic_store(&hn[idx], (unsigned short)f2bf(hnv), __ATOMIC_RELAXED,
                           __HIP_MEMORY_SCOPE_AGENT);
        if (lastg) {
          out[idx] = hnv;
          out[(1u << 20) + idx] = cn;
        }
      }
    }

    // ---- GROUP barrier (64 blocks; batch rows are independent across groups).
    // Release = vmcnt(0) inside __syncthreads (stores are write-through).
    // Acquire = invalidate-only agent fence.
    if (t < Tcur - 1) {
      __syncthreads();
      if (tid == 0) {
        __hip_atomic_fetch_add(gbar, 1u, __ATOMIC_RELAXED, __HIP_MEMORY_SCOPE_AGENT);
        unsigned tgt = (bar_base + (unsigned)(t + 1)) << 6;  // 64 arrivals/step
        while (__hip_atomic_load(gbar, __ATOMIC_RELAXED, __HIP_MEMORY_SCOPE_AGENT) < tgt)
          __builtin_amdgcn_s_sleep(2);
        __builtin_amdgcn_fence(__ATOMIC_ACQUIRE, "agent");  // inv L1+L2, no wbl2
      }
      __syncthreads();
    }

    unsigned short* tmp = hn;
    hn = (unsigned short*)hp;
    hp = tmp;
  }

  if (save_c) {
#pragma unroll
    for (int i = 0; i < 2; ++i) {
      int row = m0 + wave * 32 + i * 16 + lq * 4;
#pragma unroll
      for (int r = 0; r < 4; ++r)
        c_ws[((size_t)(row + r) << 10) + colh] = creg[i][r];
    }
  }
}

extern "C" void kernel_launch(void* const* d_in, const int* in_sizes, int n_in,
                              void* d_out, int out_size, void* d_ws, size_t ws_size,
                              hipStream_t stream) {
  const float* x = (const float*)d_in[0];
  char* ws = (char*)d_ws;
  unsigned short* wT = (unsigned short*)ws;                        // 16 MB
  float* bias_c = (float*)(ws + (16u << 20));                      // 16 KB
  unsigned* bar = (unsigned*)(ws + (16u << 20) + (32u << 10));     // 4 group counters
  unsigned short* hb0 = (unsigned short*)(ws + (17u << 20));       // 2 MB
  unsigned short* hb1 = (unsigned short*)(ws + (19u << 20));       // 2 MB
  float* c_ws = (float*)(ws + (21u << 20));                        // 4 MB
  unsigned short* xb = (unsigned short*)(ws + (25u << 20));        // Tc*2 MB

  size_t base = 25u << 20;
  size_t per_t = 10u << 20;  // xb 2MB + xp 8MB per step
  int Tc = 1;
  if (ws_size > base + per_t) {
    size_t t = (ws_size - base) / per_t;
    Tc = t > 128 ? 128 : (int)t;
  }
  unsigned short* xp = xb + ((size_t)Tc << 20);

  for (int j = 0; j < 8; ++j)
    wtrans<<<dim3(32, 32), 256, 0, stream>>>((const float*)d_in[1 + j],
                                             wT + ((size_t)j << 20));
  bias_combine<<<16, 256, 0, stream>>>(
      (const float*)d_in[9], (const float*)d_in[10], (const float*)d_in[11],
      (const float*)d_in[12], (const float*)d_in[13], (const float*)d_in[14],
      (const float*)d_in[15], (const float*)d_in[16], bias_c);

  hipMemsetAsync(hb0, 0, 2u << 20, stream);
  hipMemsetAsync(c_ws, 0, 4u << 20, stream);
  hipMemsetAsync(bar, 0, 4096, stream);

  float* out = (float*)d_out;
  unsigned short* hcur = hb0;
  unsigned short* hnxt = hb1;
  unsigned barcnt = 0;  // completed barrier-steps (per group)
  for (int t0 = 0; t0 < Sdim; t0 += Tc) {
    int Tcur = (Sdim - t0) < Tc ? (Sdim - t0) : Tc;
    xconv<<<dim3(512, Tcur), 256, 0, stream>>>(x, xb, t0, Tcur);
    xgemm<<<dim3(32, Tcur * 8), 256, 0, stream>>>(xb, wT, xp, Tcur);
    int save_c = (t0 + Tcur < Sdim) ? 1 : 0;
    lstm_persist<<<dim3(NBLK), dim3(512), 0, stream>>>(
        hcur, hnxt, c_ws, wT, bias_c, xp, out, bar, barcnt, t0, Tcur, save_c);
    barcnt += (unsigned)(Tcur - 1);
    if (Tcur & 1) {
      unsigned short* tmp = hcur;
      hcur = hnxt;
      hnxt = tmp;
    }
  }
}

// Round 11
// 5177.787 us; speedup vs baseline: 1.5252x; 1.0234x over previous
//
#include <hip/hip_runtime.h>

// LSTM: B=H=1024, S=128, I=1024.
// Round 6 (resubmit x3; R8-R10 benches never acquired a GPU): within-run A/B on
// the inter-step barrier.
//  Steps are split into two 64-step dispatches:
//   dispatch 1 (var=0): R5 barrier (64 pollers spin on one group counter line).
//   dispatch 2 (var=1): distributed sense-barrier — arrivals on 2 sub-counter
//     lines/group; ONE aggregator polls them; peers each spin on a PRIVATE
//     128B-strided go[bid] line (1 writer + 1 reader -> no same-line storm).
//  Per-block acquire fence (L2 inv) kept identical in both variants.
//  Everything else = R5: write-through h stores, gate-interleaved xp prefetch,
//  depth-4 K pipeline, LDS-resident swizzled Wh, XCD-pair group mapping.
// ws layout: wT 16MB | bias 16KB @16M | barrier area 64KB @16M+32K |
//            h0 @17M | h1 @19M | c @21M (4MB) | xb (Tc*2MB) @25M | xp after.

#define Hdim 1024
#define Sdim 128
#define NBLK 256

typedef __attribute__((ext_vector_type(8))) short short8;
typedef __attribute__((ext_vector_type(4))) float floatx4;
typedef __attribute__((ext_vector_type(4))) unsigned short ushort4v;

#define GLDS(gp, lp)                                                     \
  __builtin_amdgcn_global_load_lds(                                      \
      (const __attribute__((address_space(1))) void*)(gp),               \
      (__attribute__((address_space(3))) void*)(lp), 16, 0, 0)

static __device__ __forceinline__ short f2bf(float f) {
  unsigned u = __float_as_uint(f);
  u += 0x7fffu + ((u >> 16) & 1u);
  return (short)(u >> 16);
}
static __device__ __forceinline__ float bf2f(unsigned short u) {
  return __uint_as_float((unsigned)u << 16);
}

// ---- weight transpose + convert: dst[h][k] = src[k][h] (bf16) ----
__global__ __launch_bounds__(256) void wtrans(const float* __restrict__ src,
                                              unsigned short* __restrict__ dst) {
  __shared__ float tile[32][33];
  int h0 = blockIdx.x * 32, k0 = blockIdx.y * 32;
  int tx = threadIdx.x & 31, ty = threadIdx.x >> 5;
#pragma unroll
  for (int r = ty; r < 32; r += 8)
    tile[r][tx] = src[((size_t)(k0 + r) << 10) + h0 + tx];
  __syncthreads();
#pragma unroll
  for (int r = ty; r < 32; r += 8)
    dst[((size_t)(h0 + r) << 10) + k0 + tx] = (unsigned short)f2bf(tile[tx][r]);
}

// ---- combined bias ----
__global__ void bias_combine(const float* __restrict__ b0, const float* __restrict__ b1,
                             const float* __restrict__ b2, const float* __restrict__ b3,
                             const float* __restrict__ b4, const float* __restrict__ b5,
                             const float* __restrict__ b6, const float* __restrict__ b7,
                             float* __restrict__ bias_c) {
  int i = blockIdx.x * 256 + threadIdx.x;
  int g = i >> 10, h = i & 1023;
  const float *pa, *pb;
  switch (g) {
    case 0: pa = b0; pb = b1; break;
    case 1: pa = b2; pb = b3; break;
    case 2: pa = b4; pb = b5; break;
    default: pa = b6; pb = b7; break;
  }
  bias_c[i] = pa[h] + pb[h];
}

// ---- x fp32 -> xb bf16, chunk layout xb[b][tc][k] ----
__global__ __launch_bounds__(256) void xconv(const float* __restrict__ x,
                                             unsigned short* __restrict__ xb,
                                             int t0, int Tcur) {
  int tc = blockIdx.y;
  int tid8 = (blockIdx.x * 256 + threadIdx.x) * 8;
  int b = tid8 >> 10, k = tid8 & 1023;
  const float* src = x + ((((size_t)b << 7) + t0 + tc) << 10) + k;
  floatx4 f0 = *(const floatx4*)src;
  floatx4 f1 = *(const floatx4*)(src + 4);
  short8 o;
#pragma unroll
  for (int j = 0; j < 4; ++j) {
    o[j] = f2bf(f0[j]);
    o[4 + j] = f2bf(f1[j]);
  }
  *(short8*)(xb + (((size_t)b * Tcur + tc) << 10) + k) = o;
}

// ---- big GEMM: xp[tc][b][h*4+g] = xb[b][tc][:] @ Wx_g[:, h] (bf16, gate-interleaved) ----
__global__ __launch_bounds__(256) void xgemm(const unsigned short* __restrict__ xb,
                                             const unsigned short* __restrict__ wT,
                                             unsigned short* __restrict__ xp,
                                             int Tcur) {
  __shared__ unsigned short As[128 * 32];
  __shared__ unsigned short Bs[128 * 32];
  int tid = threadIdx.x;
  int wave = tid >> 6, lane = tid & 63;
  int ln = lane & 15, lq = lane >> 4;
  int wm = wave & 1, wn = wave >> 1;
  int srow = lane >> 2, scol = (lane & 3) * 8;
  int nt = blockIdx.x;
  int g = nt >> 3;
  int h0 = (nt & 7) * 128;
  int mt = blockIdx.y;
  int tc = mt >> 3;
  int b0 = (mt & 7) * 128;
  const unsigned short* wx = wT + ((size_t)(2 * g) << 20);

  floatx4 acc[4][4];
#pragma unroll
  for (int i = 0; i < 4; ++i)
#pragma unroll
    for (int j = 0; j < 4; ++j) acc[i][j] = (floatx4){0.f, 0.f, 0.f, 0.f};

#pragma unroll 1
  for (int k0 = 0; k0 < 1024; k0 += 32) {
    __syncthreads();
#pragma unroll
    for (int i = 0; i < 2; ++i) {
      int q = wave * 2 + i;
      GLDS(xb + (((size_t)(b0 + q * 16 + srow) * Tcur + tc) << 10) + k0 + scol,
           (char*)As + q * 1024 + lane * 16);
      GLDS(wx + ((size_t)(h0 + q * 16 + srow) << 10) + k0 + scol,
           (char*)Bs + q * 1024 + lane * 16);
    }
    __syncthreads();
    short8 a[4], b[4];
#pragma unroll
    for (int i = 0; i < 4; ++i)
      a[i] = *(const short8*)(As + (wm * 64 + i * 16 + ln) * 32 + lq * 8);
#pragma unroll
    for (int j = 0; j < 4; ++j)
      b[j] = *(const short8*)(Bs + (wn * 64 + j * 16 + ln) * 32 + lq * 8);
#pragma unroll
    for (int i = 0; i < 4; ++i)
#pragma unroll
      for (int j = 0; j < 4; ++j)
        acc[i][j] = __builtin_amdgcn_mfma_f32_16x16x32_bf16(a[i], b[j], acc[i][j], 0, 0, 0);
  }

  size_t rowbase = (size_t)tc << 10;
#pragma unroll
  for (int i = 0; i < 4; ++i) {
    int brow = b0 + wm * 64 + i * 16 + lq * 4;
#pragma unroll
    for (int j = 0; j < 4; ++j) {
      int hcol = h0 + wn * 64 + j * 16 + ln;
#pragma unroll
      for (int r = 0; r < 4; ++r)
        xp[((rowbase + brow + r) << 12) + (hcol << 2) + g] =
            (unsigned short)f2bf(acc[i][j][r]);
    }
  }
}

// ---- persistent recurrence, A/B barrier variants ----
// 4 independent m-groups (256 rows each); group = (bid&7)>>1. Each group:
// 64 blocks x (256 rows x 16 h-cols x 4 gates). 128KB LDS -> 1 block/CU.
// Barrier area (unsigned* bar):
//   [0..1KB)  : 4 group counters, 256B apart        (var 0)
//   [4..8KB)  : 8 arrival sub-counters, 128B apart  (var 1)
//   [8..40KB) : 256 per-block go flags, 128B apart  (var 1)
__global__ __launch_bounds__(512, 2) void lstm_persist(
    const unsigned short* __restrict__ hA, unsigned short* __restrict__ hB,
    float* __restrict__ c_ws, const unsigned short* __restrict__ wT,
    const float* __restrict__ bias_c, const unsigned short* __restrict__ xp,
    float* __restrict__ out, unsigned* __restrict__ bar, unsigned bar_base,
    int t0, int Tcur, int save_c, int var) {
  __shared__ unsigned short Wsh[4 * 16 * 1024];  // 128 KB, XOR-swizzled rows

  const int tid = threadIdx.x;
  const int bid = blockIdx.x;
  const int wave = tid >> 6, lane = tid & 63;
  const int ln = lane & 15, lq = lane >> 4;
  const int mg = (bid & 7) >> 1;                       // m-group 0..3
  const int hc = ((bid >> 3) << 1) | (bid & 1);        // h-tile 0..63
  const int hc0 = hc << 4;                             // 16 h-cols
  const int m0 = mg << 8;                              // 256 b-rows
  unsigned* gbar = bar + (mg << 6);                    // var0 group counter
  unsigned* sc0p = bar + 1024 + ((mg * 2) << 5);       // var1 sub-counters
  unsigned* sc1p = bar + 1024 + ((mg * 2 + 1) << 5);
  unsigned* subc = (bid & 1) ? sc1p : sc0p;
  unsigned* go = bar + 2048;                           // var1 go flags

  // ---- stage Wh slice once: Wsh[g][hc][k], byte ^= (hc&7)<<4
  for (int c = tid; c < 8192; c += 512) {
    int g = c >> 11;
    int r = c & 2047;
    int hcr = r >> 7;
    int kc = r & 127;
    short8 v = *(const short8*)(wT + (((size_t)(2 * g + 1)) << 20) +
                                ((size_t)(hc0 + hcr) << 10) + kc * 8);
    unsigned byte = ((unsigned)(g * 16 + hcr) << 11) + (unsigned)kc * 16;
    byte ^= (unsigned)(hcr & 7) << 4;
    *(short8*)((char*)Wsh + byte) = v;
  }

  const int colh = hc0 + ln;
  const float bi = bias_c[colh];
  const float bff = bias_c[1024 + colh];
  const float bgc = bias_c[2048 + colh];
  const float bo = bias_c[3072 + colh];

  // c lives in registers for the whole chunk
  float creg[2][4];
#pragma unroll
  for (int i = 0; i < 2; ++i) {
    int row = m0 + wave * 32 + i * 16 + lq * 4;
#pragma unroll
    for (int r = 0; r < 4; ++r)
      creg[i][r] = c_ws[((size_t)(row + r) << 10) + colh];
  }

  __syncthreads();  // Wsh ready

  const unsigned short* hp = hA;
  unsigned short* hn = hB;

  floatx4 acc[4][2];
  const unsigned short *hrow0, *hrow1;

  auto loadch = [&](short8 (&buf)[2][2], int c) {
#pragma unroll
    for (int s = 0; s < 2; ++s) {
      buf[s][0] = *(const short8*)(hrow0 + c * 64 + s * 32);
      buf[s][1] = *(const short8*)(hrow1 + c * 64 + s * 32);
    }
  };
  auto compch = [&](short8 (&buf)[2][2], int c) {
#pragma unroll
    for (int s = 0; s < 2; ++s) {
      int kk = c * 64 + s * 32;
#pragma unroll
      for (int g = 0; g < 4; ++g) {
        unsigned byte = (((unsigned)(g * 16 + ln) << 11) + (unsigned)(kk + lq * 8) * 2) ^
                        ((unsigned)(ln & 7) << 4);
        short8 b = *(const short8*)((const char*)Wsh + byte);
#pragma unroll
        for (int i = 0; i < 2; ++i)
          acc[g][i] =
              __builtin_amdgcn_mfma_f32_16x16x32_bf16(buf[s][i], b, acc[g][i], 0, 0, 0);
      }
    }
  };

  for (int t = 0; t < Tcur; ++t) {
    // ---- prefetch this step's xp gate-quads (hidden under the K-loop)
    ushort4v xpv[2][4];
#pragma unroll
    for (int i = 0; i < 2; ++i) {
      int rbase = m0 + wave * 32 + i * 16 + lq * 4;
#pragma unroll
      for (int r = 0; r < 4; ++r)
        xpv[i][r] = *(const ushort4v*)(xp + ((((size_t)t << 10) + rbase + r) << 12) +
                                       ((size_t)colh << 2));
    }

#pragma unroll
    for (int g = 0; g < 4; ++g)
#pragma unroll
      for (int i = 0; i < 2; ++i) acc[g][i] = (floatx4){0.f, 0.f, 0.f, 0.f};

    hrow0 = hp + ((size_t)(m0 + wave * 32 + ln) << 10) + lq * 8;
    hrow1 = hrow0 + (16 << 10);

    // ---- K-loop: 16 chunks of 64, depth-4 named-buffer pipeline, no barriers
    short8 aA[2][2], aB[2][2], aC[2][2], aD[2][2];
    loadch(aA, 0);
    loadch(aB, 1);
    loadch(aC, 2);
    loadch(aD, 3);
#pragma unroll 1
    for (int c = 0; c < 12; c += 4) {
      compch(aA, c);
      loadch(aA, c + 4);
      compch(aB, c + 1);
      loadch(aB, c + 5);
      compch(aC, c + 2);
      loadch(aC, c + 6);
      compch(aD, c + 3);
      loadch(aD, c + 7);
    }
    compch(aA, 12);
    compch(aB, 13);
    compch(aC, 14);
    compch(aD, 15);

    // ---- fused LSTM epilogue (C/D layout: col=lane&15, row=lq*4+r)
    const int lastg = (t0 + t == Sdim - 1);
#pragma unroll
    for (int i = 0; i < 2; ++i) {
      int rbase2 = m0 + wave * 32 + i * 16 + lq * 4;
#pragma unroll
      for (int r = 0; r < 4; ++r) {
        int row = rbase2 + r;
        float pi = acc[0][i][r] + bf2f(xpv[i][r][0]) + bi;
        float pf = acc[1][i][r] + bf2f(xpv[i][r][1]) + bff;
        float pg = acc[2][i][r] + bf2f(xpv[i][r][2]) + bgc;
        float po = acc[3][i][r] + bf2f(xpv[i][r][3]) + bo;
        float gi = 1.f / (1.f + __expf(-pi));
        float gf = 1.f / (1.f + __expf(-pf));
        float gg = 2.f / (1.f + __expf(-2.f * pg)) - 1.f;
        float go_ = 1.f / (1.f + __expf(-po));
        float cn = gf * creg[i][r] + gi * gg;
        float hnv = go_ * (2.f / (1.f + __expf(-2.f * cn)) - 1.f);
        creg[i][r] = cn;
        size_t idx = ((size_t)row << 10) + colh;
        __hip_atomic_store(&hn[idx], (unsigned short)f2bf(hnv), __ATOMIC_RELAXED,
                           __HIP_MEMORY_SCOPE_AGENT);
        if (lastg) {
          out[idx] = hnv;
          out[(1u << 20) + idx] = cn;
        }
      }
    }

    // ---- group barrier. Release = vmcnt(0) inside __syncthreads (stores are
    // write-through). Acquire = per-block invalidate-only agent fence.
    if (t < Tcur - 1) {
      __syncthreads();
      if (tid == 0) {
        const unsigned epoch = bar_base + (unsigned)(t + 1);
        if (var == 0) {
          // R5 baseline: 64 pollers on one line
          __hip_atomic_fetch_add(gbar, 1u, __ATOMIC_RELAXED, __HIP_MEMORY_SCOPE_AGENT);
          unsigned tgt = epoch << 6;
          while (__hip_atomic_load(gbar, __ATOMIC_RELAXED, __HIP_MEMORY_SCOPE_AGENT) < tgt)
            __builtin_amdgcn_s_sleep(2);
          __builtin_amdgcn_fence(__ATOMIC_ACQUIRE, "agent");
        } else {
          // distributed sense-barrier: 2 arrival lines, 1 aggregator, private go flags
          __hip_atomic_fetch_add(subc, 1u, __ATOMIC_RELAXED, __HIP_MEMORY_SCOPE_AGENT);
          if (hc == 0) {
            unsigned tgt = epoch << 6;
            while (__hip_atomic_load(sc0p, __ATOMIC_RELAXED, __HIP_MEMORY_SCOPE_AGENT) +
                       __hip_atomic_load(sc1p, __ATOMIC_RELAXED,
                                         __HIP_MEMORY_SCOPE_AGENT) <
                   tgt)
              __builtin_amdgcn_s_sleep(2);
            __builtin_amdgcn_fence(__ATOMIC_ACQUIRE, "agent");
#pragma unroll 1
            for (int k = 0; k < 32; ++k) {
              int pb0 = (k << 3) | (mg << 1);
              int pb1 = pb0 | 1;
              if (pb0 != bid)
                __hip_atomic_store(go + (pb0 << 5), epoch, __ATOMIC_RELAXED,
                                   __HIP_MEMORY_SCOPE_AGENT);
              __hip_atomic_store(go + (pb1 << 5), epoch, __ATOMIC_RELAXED,
                                 __HIP_MEMORY_SCOPE_AGENT);
            }
          } else {
            unsigned* myg = go + (bid << 5);
            while (__hip_atomic_load(myg, __ATOMIC_RELAXED, __HIP_MEMORY_SCOPE_AGENT) <
                   epoch)
              __builtin_amdgcn_s_sleep(2);
            __builtin_amdgcn_fence(__ATOMIC_ACQUIRE, "agent");
          }
        }
      }
      __syncthreads();
    }

    unsigned short* tmp = hn;
    hn = (unsigned short*)hp;
    hp = tmp;
  }

  if (save_c) {
#pragma unroll
    for (int i = 0; i < 2; ++i) {
      int row = m0 + wave * 32 + i * 16 + lq * 4;
#pragma unroll
      for (int r = 0; r < 4; ++r)
        c_ws[((size_t)(row + r) << 10) + colh] = creg[i][r];
    }
  }
}

extern "C" void kernel_launch(void* const* d_in, const int* in_sizes, int n_in,
                              void* d_out, int out_size, void* d_ws, size_t ws_size,
                              hipStream_t stream) {
  const float* x = (const float*)d_in[0];
  char* ws = (char*)d_ws;
  unsigned short* wT = (unsigned short*)ws;                        // 16 MB
  float* bias_c = (float*)(ws + (16u << 20));                      // 16 KB
  unsigned* bar = (unsigned*)(ws + (16u << 20) + (32u << 10));     // 64 KB barrier area
  unsigned short* hb0 = (unsigned short*)(ws + (17u << 20));       // 2 MB
  unsigned short* hb1 = (unsigned short*)(ws + (19u << 20));       // 2 MB
  float* c_ws = (float*)(ws + (21u << 20));                        // 4 MB
  unsigned short* xb = (unsigned short*)(ws + (25u << 20));        // Tc*2 MB

  size_t base = 25u << 20;
  size_t per_t = 10u << 20;  // xb 2MB + xp 8MB per step
  int Tc = 1;
  if (ws_size > base + per_t) {
    size_t t = (ws_size - base) / per_t;
    Tc = t > 64 ? 64 : (int)t;  // 64 -> two persist dispatches = A/B
  }
  unsigned short* xp = xb + ((size_t)Tc << 20);

  for (int j = 0; j < 8; ++j)
    wtrans<<<dim3(32, 32), 256, 0, stream>>>((const float*)d_in[1 + j],
                                             wT + ((size_t)j << 20));
  bias_combine<<<16, 256, 0, stream>>>(
      (const float*)d_in[9], (const float*)d_in[10], (const float*)d_in[11],
      (const float*)d_in[12], (const float*)d_in[13], (const float*)d_in[14],
      (const float*)d_in[15], (const float*)d_in[16], bias_c);

  hipMemsetAsync(hb0, 0, 2u << 20, stream);
  hipMemsetAsync(c_ws, 0, 4u << 20, stream);
  hipMemsetAsync(bar, 0, 65536, stream);

  float* out = (float*)d_out;
  unsigned short* hcur = hb0;
  unsigned short* hnxt = hb1;
  unsigned base_old = 0, base_new = 0;
  int first = 1;
  for (int t0 = 0; t0 < Sdim; t0 += Tc) {
    int Tcur = (Sdim - t0) < Tc ? (Sdim - t0) : Tc;
    xconv<<<dim3(512, Tcur), 256, 0, stream>>>(x, xb, t0, Tcur);
    xgemm<<<dim3(32, Tcur * 8), 256, 0, stream>>>(xb, wT, xp, Tcur);
    int save_c = (t0 + Tcur < Sdim) ? 1 : 0;
    int var = first ? 0 : 1;
    unsigned b = var ? base_new : base_old;
    lstm_persist<<<dim3(NBLK), dim3(512), 0, stream>>>(
        hcur, hnxt, c_ws, wT, bias_c, xp, out, bar, b, t0, Tcur, save_c, var);
    if (var)
      base_new += (unsigned)(Tcur - 1);
    else
      base_old += (unsigned)(Tcur - 1);
    first = 0;
    if (Tcur & 1) {
      unsigned short* tmp = hcur;
      hcur = hnxt;
      hnxt = tmp;
    }
  }
}